// Round 2
// baseline (424.483 us; speedup 1.0000x reference)
//
#include <hip/hip_runtime.h>
#include <math.h>

// Problem constants (fixed by setup_inputs)
#define B_   4
#define T_   1024
#define CH_  4
#define F_   481
#define K_   48
#define NCOV 16
#define TF   64   // frequency tile

// ---------------------------------------------------------------------------
// Band pack: interleave (R,I) so the hot loop does 3x8B loads instead of 6x4B.
// ---------------------------------------------------------------------------
__global__ void pack_band(const float* __restrict__ bandR,
                          const float* __restrict__ bandI,
                          float2* __restrict__ bandP) {
    int i = blockIdx.x * 256 + threadIdx.x;
    if (i < F_ * K_) bandP[i] = make_float2(bandR[i], bandI[i]);
}

// ---------------------------------------------------------------------------
// Kernel 1: one 256-thread block (4 waves) per (b,t).
//   phase 1: normalized hermitian covariance tile (+halo) -> LDS (all threads)
//   phase 2: phase-adjusted cov (adj) -> LDS, |cov|*w/|w| (all threads)
//   phase 3: bc[k,c] += adj[f,c]*band[f,k]; F interleaved across the 4 waves
//   reduce : cross-wave sum of the 12 complex accumulators via LDS
//   epilogue (wave 0): ds normalize (shfl over c-quad), c2pv projection,
//                      store real output directly into d_out (b,k,t,p).
// ---------------------------------------------------------------------------
template<bool PACKED>
__global__ __launch_bounds__(256) void pv_stage1(
    const float* __restrict__ binsR, const float* __restrict__ binsI,
    const float* __restrict__ bandR, const float* __restrict__ bandI,
    const float2* __restrict__ bandP,
    const float* __restrict__ c2pR,  const float* __restrict__ c2pI,
    float* __restrict__ out)
{
    // packed cov row: [d0 d1 d2 d3 | re01 im01 re02 im02 re03 im03 re12 im12
    //                  re13 im13 re23 im23]; stride 20 keeps float4 align
    __shared__ float covS[TF + 3][20];
    __shared__ float adjS[TF][36];      // stride 36: fl shifts banks by 4, 16B-aligned
    __shared__ float red[3 * 64 * 13];  // cross-wave reduce, stride 13 (odd) per lane

    const int tid  = threadIdx.x;
    const int lane = tid & 63;
    const int w    = tid >> 6;          // wave 0..3
    const int blk  = blockIdx.x;        // b*T + t
    const int b    = blk >> 10;
    const int t    = blk & (T_ - 1);
    const int cq   = lane & 3;          // c-quad: c in [4cq, 4cq+3]
    const int kq   = lane >> 2;         // 0..15 : k in {kq, kq+16, kq+32}

    const float* xr = binsR + (size_t)(b * T_ + t) * CH_ * F_;
    const float* xi = binsI + (size_t)(b * T_ + t) * CH_ * F_;

    float accr[12], acci[12];           // [cc*3 + r]
    #pragma unroll
    for (int q = 0; q < 12; ++q) { accr[q] = 0.f; acci[q] = 0.f; }

    const int ntiles = (F_ + TF - 1) / TF;
    for (int tile = 0; tile < ntiles; ++tile) {
        const int ts = tile * TF;
        const int te = min(F_, ts + TF);
        const int tl = te - ts;
        const int r0 = max(0, ts - 1);
        const int r1 = min(F_ - 1, te + 1);
        const int rn = r1 - r0 + 1;     // <= TF+3

        // ---- phase 1: normalized covariance (parallel over rows) ----
        for (int iq = tid; iq < rn; iq += 256) {
            const int f = r0 + iq;
            float a0r = xr[f],          a0i = xi[f];
            float a1r = xr[F_ + f],     a1i = xi[F_ + f];
            float a2r = xr[2*F_ + f],   a2i = xi[2*F_ + f];
            float a3r = xr[3*F_ + f],   a3i = xi[3*F_ + f];
            float d0 = a0r*a0r + a0i*a0i;
            float d1 = a1r*a1r + a1i*a1i;
            float d2 = a2r*a2r + a2i*a2i;
            float d3 = a3r*a3r + a3i*a3i;
            float pinv = 1.0f / fmaxf(d0 + d1 + d2 + d3, 1e-20f);
            float4* row4 = reinterpret_cast<float4*>(covS[iq]);
            row4[0] = make_float4(d0*pinv, d1*pinv, d2*pinv, d3*pinv);
            row4[1] = make_float4((a0r*a1r + a0i*a1i)*pinv, (a0i*a1r - a0r*a1i)*pinv,
                                  (a0r*a2r + a0i*a2i)*pinv, (a0i*a2r - a0r*a2i)*pinv);
            row4[2] = make_float4((a0r*a3r + a0i*a3i)*pinv, (a0i*a3r - a0r*a3i)*pinv,
                                  (a1r*a2r + a1i*a2i)*pinv, (a1i*a2r - a1r*a2i)*pinv);
            row4[3] = make_float4((a1r*a3r + a1i*a3i)*pinv, (a1i*a3r - a1r*a3i)*pinv,
                                  (a2r*a3r + a2i*a3i)*pinv, (a2i*a3r - a2r*a3i)*pinv);
        }
        __syncthreads();

        // ---- phase 2: adj = |cov[f]| * w/|w|, w = conj(cov[g])*cov[g+2] ----
        for (int q = tid; q < tl * NCOV; q += 256) {
            const int fl = q >> 4, c = q & 15;
            const int i = c >> 2, j = c & 3;
            const int fg = ts + fl;
            const float* rowF = covS[fg - r0];
            float sr, si;
            if (i == j) {
                sr = rowF[i]; si = 0.f;
            } else {
                const int a  = min(i, j), bb = max(i, j);
                const int off = 4 + 2 * ((a == 0) ? (bb - 1) : (a == 1) ? (bb + 1) : 5);
                float pfr = rowF[off], pfi = rowF[off + 1];
                int g = fg - 1; g = g < 0 ? 0 : (g > F_ - 3 ? F_ - 3 : g);
                const float* rowL = covS[g - r0];
                const float* rowR = covS[g + 2 - r0];
                float Lr = rowL[off], Li = rowL[off + 1];
                float Rr = rowR[off], Ri = rowR[off + 1];
                if (i > j) { pfi = -pfi; Li = -Li; Ri = -Ri; }
                float wr = Lr * Rr + Li * Ri;
                float wi = Lr * Ri - Li * Rr;
                float n2 = wr * wr + wi * wi;
                float mag = sqrtf(pfr * pfr + pfi * pfi);
                if (n2 > 0.f) { float s = mag * rsqrtf(n2); sr = wr * s; si = wi * s; }
                else          { sr = mag; si = 0.f; }   // angle(0)=0
            }
            *reinterpret_cast<float2*>(&adjS[fl][2*c]) = make_float2(sr, si);
        }
        __syncthreads();

        // ---- phase 3: accumulate bc; fl interleaved across waves ----
        auto body = [&](int fl) {
            const float4* ap = reinterpret_cast<const float4*>(&adjS[fl][8 * cq]);
            float4 A  = ap[0];            // c0: (x,y), c1: (z,w)
            float4 Bv = ap[1];            // c2, c3
            float br[3], bi[3];
            if (PACKED) {
                const float2* bp = bandP + (size_t)(ts + fl) * K_ + kq;
                float2 b0 = bp[0], b1 = bp[16], b2 = bp[32];
                br[0] = b0.x; bi[0] = b0.y;
                br[1] = b1.x; bi[1] = b1.y;
                br[2] = b2.x; bi[2] = b2.y;
            } else {
                const int fb = (ts + fl) * K_ + kq;
                br[0] = bandR[fb];      bi[0] = bandI[fb];
                br[1] = bandR[fb + 16]; bi[1] = bandI[fb + 16];
                br[2] = bandR[fb + 32]; bi[2] = bandI[fb + 32];
            }
            float ar[4] = {A.x, A.z, Bv.x, Bv.z};
            float ai[4] = {A.y, A.w, Bv.y, Bv.w};
            #pragma unroll
            for (int cc = 0; cc < 4; ++cc) {
                #pragma unroll
                for (int r = 0; r < 3; ++r) {
                    accr[cc*3+r] = fmaf(ar[cc], br[r], fmaf(-ai[cc], bi[r], accr[cc*3+r]));
                    acci[cc*3+r] = fmaf(ar[cc], bi[r], fmaf( ai[cc], br[r], acci[cc*3+r]));
                }
            }
        };
        if (tl == TF) {
            #pragma unroll 4
            for (int i = 0; i < TF / 4; ++i) body(w + 4 * i);
        } else {
            for (int fl = w; fl < tl; fl += 4) body(fl);
        }
        __syncthreads();   // before next tile overwrites LDS
    }

    // ---- cross-wave reduction of accumulators (waves 1..3 -> wave 0) ----
    if (w > 0) {
        float* r = &red[(((w - 1) << 6) + lane) * 13];
        #pragma unroll
        for (int q = 0; q < 12; ++q) r[q] = accr[q];
    }
    __syncthreads();
    if (w == 0) {
        #pragma unroll
        for (int q = 0; q < 12; ++q)
            accr[q] += red[lane*13 + q] + red[(64+lane)*13 + q] + red[(128+lane)*13 + q];
    }
    __syncthreads();
    if (w > 0) {
        float* r = &red[(((w - 1) << 6) + lane) * 13];
        #pragma unroll
        for (int q = 0; q < 12; ++q) r[q] = acci[q];
    }
    __syncthreads();
    if (w != 0) return;   // all barriers matched; wave 0 finishes alone
    #pragma unroll
    for (int q = 0; q < 12; ++q)
        acci[q] += red[lane*13 + q] + red[(64+lane)*13 + q] + red[(128+lane)*13 + q];

    // ---- epilogue (wave 0 only) ----
    float dsi[3];
    #pragma unroll
    for (int r = 0; r < 3; ++r) {
        float d = (cq == 0) ? accr[0 + r] :
                  (cq == 1) ? accr[3 + r] :
                  (cq == 2) ? accr[6 + r] : accr[9 + r];
        d += __shfl_xor(d, 1, 64);
        d += __shfl_xor(d, 2, 64);
        dsi[r] = 1.0f / fmaxf(d, 1e-20f);
    }
    #pragma unroll
    for (int cc = 0; cc < 4; ++cc)
        #pragma unroll
        for (int r = 0; r < 3; ++r) {
            accr[cc*3+r] *= dsi[r];
            acci[cc*3+r] *= dsi[r];
        }

    // z[k][p] = Re( c2pv[p,:] . bc_norm[k,:] ), partial over lane's 4 c's
    float zp[48];   // [p*3 + r]
    #pragma unroll
    for (int q = 0; q < 48; ++q) zp[q] = 0.f;
    #pragma unroll
    for (int p = 0; p < 16; ++p) {
        const float4 cr4 = *reinterpret_cast<const float4*>(c2pR + p * 16 + 4 * cq);
        const float4 ci4 = *reinterpret_cast<const float4*>(c2pI + p * 16 + 4 * cq);
        float crr[4] = {cr4.x, cr4.y, cr4.z, cr4.w};
        float cii[4] = {ci4.x, ci4.y, ci4.z, ci4.w};
        #pragma unroll
        for (int cc = 0; cc < 4; ++cc)
            #pragma unroll
            for (int r = 0; r < 3; ++r)
                zp[p*3+r] = fmaf(crr[cc], accr[cc*3+r],
                            fmaf(-cii[cc], acci[cc*3+r], zp[p*3+r]));
    }
    #pragma unroll
    for (int q = 0; q < 48; ++q) {
        zp[q] += __shfl_xor(zp[q], 1, 64);
        zp[q] += __shfl_xor(zp[q], 2, 64);
    }
    // store: out[((b*K + k)*T + t)*16 + p]; lane owns p in [4cq, 4cq+3]
    #pragma unroll
    for (int p = 0; p < 16; ++p) {
        if (cq == (p >> 2)) {
            #pragma unroll
            for (int r = 0; r < 3; ++r) {
                const int k = kq + 16 * r;
                out[(size_t)((b * K_ + k) * T_ + t) * 16 + p] = zp[p*3+r];
            }
        }
    }
}

// ---------------------------------------------------------------------------
// Kernel 2: in-place IIR over t. One block per (b,k); 512 threads =
// (p in 0..15) x (chunk j in 0..31), chunk = 32 (keeps VGPRs ~50, no spill).
//   y_t = p_t + a^{s+1} * Y_chunk,   Y_j = E_{j-1}, E_m = F_m + a^32 E_{m-1}
// ---------------------------------------------------------------------------
__global__ __launch_bounds__(512) void pv_iir(float* __restrict__ out,
                                              const float* __restrict__ tau)
{
    const int p  = threadIdx.x & 15;
    const int j  = threadIdx.x >> 4;     // chunk index 0..31
    const int bk = blockIdx.x;           // b*K + k
    const int k  = bk % K_;
    const float a   = expf(-10.0f / tau[k]);
    const float oma = 1.0f - a;
    float* base = out + (size_t)bk * T_ * 16 + j * 32 * 16 + p;

    float y[32];
    float cur = 0.f;
    #pragma unroll
    for (int s = 0; s < 32; ++s) {
        float x = base[s * 16];
        if (j == 0 && s == 0) cur = x;          // ys[0] = xs[0] exactly
        else                  cur = fmaf(a, cur, oma * x);
        y[s] = cur;
    }

    __shared__ float Fc[32][17];
    Fc[j][p] = cur;                              // chunk-final partial
    __syncthreads();

    float a32 = a;
    #pragma unroll
    for (int q = 0; q < 5; ++q) a32 *= a32;      // a^32

    float Y = 0.f;
    if (j > 0) {
        float E = Fc[0][p];                      // chunk 0 is exact
        for (int i = 1; i < j; ++i) E = fmaf(a32, E, Fc[i][p]);
        Y = E;
    }

    float pw = a;
    #pragma unroll
    for (int s = 0; s < 32; ++s) {
        base[s * 16] = fmaf(pw, Y, y[s]);
        pw *= a;
    }
}

extern "C" void kernel_launch(void* const* d_in, const int* in_sizes, int n_in,
                              void* d_out, int out_size, void* d_ws, size_t ws_size,
                              hipStream_t stream) {
    const float* binsR = (const float*)d_in[0];
    const float* binsI = (const float*)d_in[1];
    const float* bandR = (const float*)d_in[2];
    const float* bandI = (const float*)d_in[3];
    const float* c2pR  = (const float*)d_in[4];
    const float* c2pI  = (const float*)d_in[5];
    const float* tau   = (const float*)d_in[6];
    float* out = (float*)d_out;

    const size_t packBytes = sizeof(float2) * (size_t)F_ * K_;
    if (ws_size >= packBytes) {
        float2* bandP = (float2*)d_ws;
        pack_band<<<(F_ * K_ + 255) / 256, 256, 0, stream>>>(bandR, bandI, bandP);
        pv_stage1<true><<<B_ * T_, 256, 0, stream>>>(binsR, binsI, bandR, bandI,
                                                     bandP, c2pR, c2pI, out);
    } else {
        pv_stage1<false><<<B_ * T_, 256, 0, stream>>>(binsR, binsI, bandR, bandI,
                                                      nullptr, c2pR, c2pI, out);
    }
    pv_iir<<<B_ * K_, 512, 0, stream>>>(out, tau);
}

// Round 3
// 189.429 us; speedup vs baseline: 2.2409x; 2.2409x over previous
//
#include <hip/hip_runtime.h>
#include <math.h>

// Problem constants (fixed by setup_inputs)
#define B_    4
#define T_    1024
#define CH_   4
#define F_    481
#define K_    48
#define NCOV  16
#define TF    64          // frequency tile
#define NTILES 8          // ceil(481/64)
#define KSTEPS 32         // NTILES*4 K-steps of 32 slots (K_eff = 2*481 -> padded 1024)
#define NT_   3           // n-tiles over K_=48 (16 cols each)
#define NCH_  2           // chains: 0 = Cr, 1 = Ci

typedef _Float16 half8  __attribute__((ext_vector_type(8)));
typedef _Float16 half2v __attribute__((ext_vector_type(2)));
typedef float    f32x4  __attribute__((ext_vector_type(4)));

#define BBUF_ELEMS (NCH_ * NT_ * KSTEPS * 512)        // 98304 f16
#define BBUF_BYTES (BBUF_ELEMS * 2)                   // 196608 B
#define WS_NEEDED  (BBUF_BYTES + K_ * (int)sizeof(float))

// ---------------------------------------------------------------------------
// Pack band into MFMA-ready B fragments (runs every launch; ws is re-poisoned).
// Layout: Bbuf[((chain*3+nt)*KSTEPS + gstep)*512 + lane*8 + j]
//   kk = gstep*32 + (lane>>4)*8 + j ; f = kk>>1 ; k = nt*16 + (lane&15)
//   chain Cr: even slot -> br, odd -> -bi ; chain Ci: even -> bi, odd -> br
// ---------------------------------------------------------------------------
__global__ void pack_bfrag(const float* __restrict__ bandR,
                           const float* __restrict__ bandI,
                           _Float16* __restrict__ Bbuf) {
    int e = blockIdx.x * 256 + threadIdx.x;
    if (e >= BBUF_ELEMS) return;
    const int j     = e & 7;
    const int lane  = (e >> 3) & 63;
    const int gstep = (e >> 9) & 31;
    const int u     = e >> 14;          // chain*3 + nt, 0..5
    const int nt    = u % 3;
    const int chain = u / 3;
    const int kk = gstep * 32 + ((lane >> 4) << 3) + j;
    const int f  = kk >> 1;
    const int k  = nt * 16 + (lane & 15);
    float v = 0.f;
    if (f < F_) {
        float br = bandR[f * K_ + k];
        float bi = bandI[f * K_ + k];
        v = (chain == 0) ? ((kk & 1) ? -bi : br)
                         : ((kk & 1) ?  br : bi);
    }
    Bbuf[e] = (_Float16)v;
}

// ds[k] = sum_f Re(band[f,k])  (trace(adj)==1 exactly; see analysis)
__global__ void calc_dsum(const float* __restrict__ bandR,
                          float* __restrict__ dsum) {
    const int k = blockIdx.x;
    float s = 0.f;
    for (int f = threadIdx.x; f < F_; f += 64) s += bandR[f * K_ + k];
    #pragma unroll
    for (int m = 1; m < 64; m <<= 1) s += __shfl_xor(s, m, 64);
    if (threadIdx.x == 0) dsum[k] = s;
}

// ---------------------------------------------------------------------------
// Stage 1: one wave per (b,t).
//   phase 1: normalized hermitian cov tile (+halo) -> LDS (fp32, packed 20)
//   phase 2: adj = |cov|*w/|w| computed fp32, written DIRECTLY as f16 into
//            pre-swizzled A-fragment layout in LDS (half2 = (ar,ai) per slot)
//   phase 3: 4 K-steps x [1 ds_read_b128 A-frag + 6 global B-frags + 6 MFMA]
//   epilogue: ds-normalize (exact dsum), c2pv projection, float4 stores.
// ---------------------------------------------------------------------------
__global__ __launch_bounds__(64, 4) void pv_stage1(
    const float* __restrict__ binsR, const float* __restrict__ binsI,
    const _Float16* __restrict__ Bbuf, const float* __restrict__ dsum,
    const float* __restrict__ c2pR,  const float* __restrict__ c2pI,
    float* __restrict__ out)
{
    __shared__ float covS[TF + 3][20];         // 5360 B
    __shared__ _Float16 afrag[4 * 512];        // 4 KiB: [step][lane][8]

    const int lane = threadIdx.x;
    const int blk  = blockIdx.x;               // b*T + t
    const int b    = blk >> 10;
    const int t    = blk & (T_ - 1);

    const float* xr = binsR + (size_t)(b * T_ + t) * CH_ * F_;
    const float* xi = binsI + (size_t)(b * T_ + t) * CH_ * F_;

    f32x4 acc[6];                               // [chain*3 + nt]
    #pragma unroll
    for (int u = 0; u < 6; ++u) acc[u] = (f32x4){0.f, 0.f, 0.f, 0.f};

    for (int tile = 0; tile < NTILES; ++tile) {
        const int ts = tile * TF;
        const int tl = min(F_, ts + TF) - ts;
        const int r0 = max(0, ts - 1);
        const int r1 = min(F_ - 1, ts + tl);    // max row needed is fg+1 <= ts+tl
        const int rn = r1 - r0 + 1;             // <= 66

        // ---- phase 1: normalized covariance ----
        for (int iq = lane; iq < rn; iq += 64) {
            const int f = r0 + iq;
            float a0r = xr[f],          a0i = xi[f];
            float a1r = xr[F_ + f],     a1i = xi[F_ + f];
            float a2r = xr[2*F_ + f],   a2i = xi[2*F_ + f];
            float a3r = xr[3*F_ + f],   a3i = xi[3*F_ + f];
            float d0 = a0r*a0r + a0i*a0i;
            float d1 = a1r*a1r + a1i*a1i;
            float d2 = a2r*a2r + a2i*a2i;
            float d3 = a3r*a3r + a3i*a3i;
            float pinv = 1.0f / fmaxf(d0 + d1 + d2 + d3, 1e-20f);
            float4* row4 = reinterpret_cast<float4*>(covS[iq]);
            row4[0] = make_float4(d0*pinv, d1*pinv, d2*pinv, d3*pinv);
            row4[1] = make_float4((a0r*a1r + a0i*a1i)*pinv, (a0i*a1r - a0r*a1i)*pinv,
                                  (a0r*a2r + a0i*a2i)*pinv, (a0i*a2r - a0r*a2i)*pinv);
            row4[2] = make_float4((a0r*a3r + a0i*a3i)*pinv, (a0i*a3r - a0r*a3i)*pinv,
                                  (a1r*a2r + a1i*a2i)*pinv, (a1i*a2r - a1r*a2i)*pinv);
            row4[3] = make_float4((a1r*a3r + a1i*a3i)*pinv, (a1i*a3r - a1r*a3i)*pinv,
                                  (a2r*a3r + a2i*a3i)*pinv, (a2i*a3r - a2r*a3i)*pinv);
        }
        __syncthreads();

        // ---- phase 2: adj -> f16 A-fragments (pre-swizzled) ----
        for (int q = lane; q < TF * NCOV; q += 64) {
            const int fl = q >> 4, c = q & 15;
            half2v hv;
            if (fl >= tl) {
                hv[0] = (_Float16)0.f; hv[1] = (_Float16)0.f;  // K pad
            } else {
                const int i = c >> 2, jj = c & 3;
                const int fg = ts + fl;
                const float* rowF = covS[fg - r0];
                float sr, si;
                if (i == jj) {
                    sr = rowF[i]; si = 0.f;
                } else {
                    const int a  = min(i, jj), b2 = max(i, jj);
                    const int off = 4 + 2 * ((a == 0) ? (b2 - 1) : (a == 1) ? (b2 + 1) : 5);
                    float pfr = rowF[off], pfi = rowF[off + 1];
                    int g = fg - 1; g = g < 0 ? 0 : (g > F_ - 3 ? F_ - 3 : g);
                    const float* rowL = covS[g - r0];
                    const float* rowR = covS[g + 2 - r0];
                    float Lr = rowL[off], Li = rowL[off + 1];
                    float Rr = rowR[off], Ri = rowR[off + 1];
                    if (i > jj) { pfi = -pfi; Li = -Li; Ri = -Ri; }
                    float wr = Lr * Rr + Li * Ri;
                    float wi = Lr * Ri - Li * Rr;
                    float n2 = wr * wr + wi * wi;
                    float mag = sqrtf(pfr * pfr + pfi * pfi);
                    if (n2 > 0.f) { float s = mag * rsqrtf(n2); sr = wr * s; si = wi * s; }
                    else          { sr = mag; si = 0.f; }
                }
                hv[0] = (_Float16)sr; hv[1] = (_Float16)si;
            }
            // slot kk0 = 2*fl (ar), kk0+1 (ai): same lane slot, adjacent j
            const int kk0  = 2 * fl;
            const int st   = fl >> 4;                 // K-step within tile
            const int grp  = (kk0 & 31) >> 3;
            const int lidx = grp * 16 + c;
            *reinterpret_cast<half2v*>(&afrag[st * 512 + lidx * 8 + (kk0 & 7)]) = hv;
        }
        __syncthreads();

        // ---- phase 3: MFMA over this tile's 4 K-steps ----
        #pragma unroll
        for (int s = 0; s < 4; ++s) {
            half8 A = *reinterpret_cast<const half8*>(&afrag[s * 512 + lane * 8]);
            const int gstep = tile * 4 + s;
            #pragma unroll
            for (int u = 0; u < 6; ++u) {
                half8 Bv = *reinterpret_cast<const half8*>(
                    &Bbuf[(size_t)((u * KSTEPS + gstep) << 9) + lane * 8]);
                acc[u] = __builtin_amdgcn_mfma_f32_16x16x32_f16(A, Bv, acc[u], 0, 0, 0);
            }
        }
        __syncthreads();   // before next tile overwrites LDS
    }

    // ---- epilogue: normalize + c2pv projection ----
    // D layout: col(lane&15) = k within n-tile, row((lane>>4)*4+reg) = c
    const int kcol = lane & 15;
    const int qg   = lane >> 4;
    #pragma unroll
    for (int nt = 0; nt < NT_; ++nt) {
        const float d   = dsum[nt * 16 + kcol];
        const float dsi = 1.0f / fmaxf(d, 1e-20f);
        float crn[4], cin[4];
        #pragma unroll
        for (int r = 0; r < 4; ++r) {
            crn[r] = acc[nt][r] * dsi;          // chain 0 = Cr
            cin[r] = acc[3 + nt][r] * dsi;      // chain 1 = Ci
        }
        f32x4 pv4[4];
        #pragma unroll
        for (int p = 0; p < 16; ++p) {
            const float4 cr = *reinterpret_cast<const float4*>(c2pR + p * 16 + 4 * qg);
            const float4 ci = *reinterpret_cast<const float4*>(c2pI + p * 16 + 4 * qg);
            float s = cr.x * crn[0] + cr.y * crn[1] + cr.z * crn[2] + cr.w * crn[3]
                    - ci.x * cin[0] - ci.y * cin[1] - ci.z * cin[2] - ci.w * cin[3];
            pv4[p >> 2][p & 3] = s;
        }
        #pragma unroll
        for (int p4 = 0; p4 < 4; ++p4)
            #pragma unroll
            for (int e = 0; e < 4; ++e) {
                pv4[p4][e] += __shfl_xor(pv4[p4][e], 16, 64);
                pv4[p4][e] += __shfl_xor(pv4[p4][e], 32, 64);
            }
        if (qg == 0) {
            float* ob = out + ((size_t)(b * K_ + nt * 16 + kcol) * T_ + t) * 16;
            #pragma unroll
            for (int p4 = 0; p4 < 4; ++p4)
                *reinterpret_cast<f32x4*>(&ob[p4 * 4]) = pv4[p4];
        }
    }
}

// ---------------------------------------------------------------------------
// Fallback (ws too small for Bbuf): R1 scalar path, known-correct.
// ---------------------------------------------------------------------------
__global__ __launch_bounds__(64) void pv_stage1_scalar(
    const float* __restrict__ binsR, const float* __restrict__ binsI,
    const float* __restrict__ bandR, const float* __restrict__ bandI,
    const float* __restrict__ c2pR,  const float* __restrict__ c2pI,
    float* __restrict__ out)
{
    __shared__ float covS[TF + 3][20];
    __shared__ float adjS[TF][32];
    const int lane = threadIdx.x;
    const int blk  = blockIdx.x;
    const int b = blk >> 10, t = blk & (T_ - 1);
    const int cq = lane & 3, kq = lane >> 2;
    const float* xr = binsR + (size_t)(b * T_ + t) * CH_ * F_;
    const float* xi = binsI + (size_t)(b * T_ + t) * CH_ * F_;
    float accr[12], acci[12];
    #pragma unroll
    for (int q = 0; q < 12; ++q) { accr[q] = 0.f; acci[q] = 0.f; }
    const int ntiles = (F_ + TF - 1) / TF;
    for (int tile = 0; tile < ntiles; ++tile) {
        const int ts = tile * TF;
        const int te = min(F_, ts + TF);
        const int tl = te - ts;
        const int r0 = max(0, ts - 1);
        const int r1 = min(F_ - 1, te + 1);
        const int rn = r1 - r0 + 1;
        for (int iq = lane; iq < rn; iq += 64) {
            const int f = r0 + iq;
            float a0r = xr[f], a0i = xi[f];
            float a1r = xr[F_ + f], a1i = xi[F_ + f];
            float a2r = xr[2*F_ + f], a2i = xi[2*F_ + f];
            float a3r = xr[3*F_ + f], a3i = xi[3*F_ + f];
            float d0 = a0r*a0r + a0i*a0i, d1 = a1r*a1r + a1i*a1i;
            float d2 = a2r*a2r + a2i*a2i, d3 = a3r*a3r + a3i*a3i;
            float pinv = 1.0f / fmaxf(d0 + d1 + d2 + d3, 1e-20f);
            float4* row4 = reinterpret_cast<float4*>(covS[iq]);
            row4[0] = make_float4(d0*pinv, d1*pinv, d2*pinv, d3*pinv);
            row4[1] = make_float4((a0r*a1r + a0i*a1i)*pinv, (a0i*a1r - a0r*a1i)*pinv,
                                  (a0r*a2r + a0i*a2i)*pinv, (a0i*a2r - a0r*a2i)*pinv);
            row4[2] = make_float4((a0r*a3r + a0i*a3i)*pinv, (a0i*a3r - a0r*a3i)*pinv,
                                  (a1r*a2r + a1i*a2i)*pinv, (a1i*a2r - a1r*a2i)*pinv);
            row4[3] = make_float4((a1r*a3r + a1i*a3i)*pinv, (a1i*a3r - a1r*a3i)*pinv,
                                  (a2r*a3r + a2i*a3i)*pinv, (a2i*a3r - a2r*a3i)*pinv);
        }
        __syncthreads();
        for (int q = lane; q < tl * NCOV; q += 64) {
            const int fl = q >> 4, c = q & 15;
            const int i = c >> 2, j = c & 3;
            const int fg = ts + fl;
            const float* rowF = covS[fg - r0];
            if (i == j) { adjS[fl][2*c] = rowF[i]; adjS[fl][2*c+1] = 0.f; }
            else {
                const int a = min(i, j), bb = max(i, j);
                const int off = 4 + 2 * ((a == 0) ? (bb - 1) : (a == 1) ? (bb + 1) : 5);
                float pfr = rowF[off], pfi = rowF[off + 1];
                int g = fg - 1; g = g < 0 ? 0 : (g > F_ - 3 ? F_ - 3 : g);
                const float* rowL = covS[g - r0];
                const float* rowR = covS[g + 2 - r0];
                float Lr = rowL[off], Li = rowL[off + 1];
                float Rr = rowR[off], Ri = rowR[off + 1];
                if (i > j) { pfi = -pfi; Li = -Li; Ri = -Ri; }
                float wr = Lr*Rr + Li*Ri, wi = Lr*Ri - Li*Rr;
                float n2 = wr*wr + wi*wi;
                float mag = sqrtf(pfr*pfr + pfi*pfi);
                float sr, si;
                if (n2 > 0.f) { float s = mag * rsqrtf(n2); sr = wr*s; si = wi*s; }
                else { sr = mag; si = 0.f; }
                adjS[fl][2*c] = sr; adjS[fl][2*c+1] = si;
            }
        }
        __syncthreads();
        for (int fl = 0; fl < tl; ++fl) {
            const float4* ap = reinterpret_cast<const float4*>(&adjS[fl][8 * cq]);
            float4 A = ap[0], Bv = ap[1];
            const int fb = (ts + fl) * K_ + kq;
            float br[3], bi[3];
            br[0] = bandR[fb];      bi[0] = bandI[fb];
            br[1] = bandR[fb + 16]; bi[1] = bandI[fb + 16];
            br[2] = bandR[fb + 32]; bi[2] = bandI[fb + 32];
            float ar[4] = {A.x, A.z, Bv.x, Bv.z};
            float ai[4] = {A.y, A.w, Bv.y, Bv.w};
            #pragma unroll
            for (int cc = 0; cc < 4; ++cc)
                #pragma unroll
                for (int r = 0; r < 3; ++r) {
                    accr[cc*3+r] = fmaf(ar[cc], br[r], fmaf(-ai[cc], bi[r], accr[cc*3+r]));
                    acci[cc*3+r] = fmaf(ar[cc], bi[r], fmaf( ai[cc], br[r], acci[cc*3+r]));
                }
        }
        __syncthreads();
    }
    float dsi[3];
    #pragma unroll
    for (int r = 0; r < 3; ++r) {
        float d = (cq == 0) ? accr[r] : (cq == 1) ? accr[3+r] :
                  (cq == 2) ? accr[6+r] : accr[9+r];
        d += __shfl_xor(d, 1, 64);
        d += __shfl_xor(d, 2, 64);
        dsi[r] = 1.0f / fmaxf(d, 1e-20f);
    }
    #pragma unroll
    for (int cc = 0; cc < 4; ++cc)
        #pragma unroll
        for (int r = 0; r < 3; ++r) { accr[cc*3+r] *= dsi[r]; acci[cc*3+r] *= dsi[r]; }
    float zp[48];
    #pragma unroll
    for (int q = 0; q < 48; ++q) zp[q] = 0.f;
    #pragma unroll
    for (int p = 0; p < 16; ++p) {
        const float4 cr4 = *reinterpret_cast<const float4*>(c2pR + p*16 + 4*cq);
        const float4 ci4 = *reinterpret_cast<const float4*>(c2pI + p*16 + 4*cq);
        float crr[4] = {cr4.x, cr4.y, cr4.z, cr4.w};
        float cii[4] = {ci4.x, ci4.y, ci4.z, ci4.w};
        #pragma unroll
        for (int cc = 0; cc < 4; ++cc)
            #pragma unroll
            for (int r = 0; r < 3; ++r)
                zp[p*3+r] = fmaf(crr[cc], accr[cc*3+r],
                            fmaf(-cii[cc], acci[cc*3+r], zp[p*3+r]));
    }
    #pragma unroll
    for (int q = 0; q < 48; ++q) {
        zp[q] += __shfl_xor(zp[q], 1, 64);
        zp[q] += __shfl_xor(zp[q], 2, 64);
    }
    #pragma unroll
    for (int p = 0; p < 16; ++p)
        if (cq == (p >> 2))
            #pragma unroll
            for (int r = 0; r < 3; ++r)
                out[(size_t)((b * K_ + kq + 16*r) * T_ + t) * 16 + p] = zp[p*3+r];
}

// ---------------------------------------------------------------------------
// Kernel 2: in-place IIR over t (unchanged from R2 — correct).
// ---------------------------------------------------------------------------
__global__ __launch_bounds__(512) void pv_iir(float* __restrict__ out,
                                              const float* __restrict__ tau)
{
    const int p  = threadIdx.x & 15;
    const int j  = threadIdx.x >> 4;
    const int bk = blockIdx.x;
    const int k  = bk % K_;
    const float a   = expf(-10.0f / tau[k]);
    const float oma = 1.0f - a;
    float* base = out + (size_t)bk * T_ * 16 + j * 32 * 16 + p;

    float y[32];
    float cur = 0.f;
    #pragma unroll
    for (int s = 0; s < 32; ++s) {
        float x = base[s * 16];
        if (j == 0 && s == 0) cur = x;
        else                  cur = fmaf(a, cur, oma * x);
        y[s] = cur;
    }
    __shared__ float Fc[32][17];
    Fc[j][p] = cur;
    __syncthreads();
    float a32 = a;
    #pragma unroll
    for (int q = 0; q < 5; ++q) a32 *= a32;
    float Y = 0.f;
    if (j > 0) {
        float E = Fc[0][p];
        for (int i = 1; i < j; ++i) E = fmaf(a32, E, Fc[i][p]);
        Y = E;
    }
    float pw = a;
    #pragma unroll
    for (int s = 0; s < 32; ++s) {
        base[s * 16] = fmaf(pw, Y, y[s]);
        pw *= a;
    }
}

extern "C" void kernel_launch(void* const* d_in, const int* in_sizes, int n_in,
                              void* d_out, int out_size, void* d_ws, size_t ws_size,
                              hipStream_t stream) {
    const float* binsR = (const float*)d_in[0];
    const float* binsI = (const float*)d_in[1];
    const float* bandR = (const float*)d_in[2];
    const float* bandI = (const float*)d_in[3];
    const float* c2pR  = (const float*)d_in[4];
    const float* c2pI  = (const float*)d_in[5];
    const float* tau   = (const float*)d_in[6];
    float* out = (float*)d_out;

    if (ws_size >= (size_t)WS_NEEDED) {
        _Float16* Bbuf = (_Float16*)d_ws;
        float*    dsum = (float*)((char*)d_ws + BBUF_BYTES);
        pack_bfrag<<<(BBUF_ELEMS + 255) / 256, 256, 0, stream>>>(bandR, bandI, Bbuf);
        calc_dsum<<<K_, 64, 0, stream>>>(bandR, dsum);
        pv_stage1<<<B_ * T_, 64, 0, stream>>>(binsR, binsI, Bbuf, dsum,
                                              c2pR, c2pI, out);
    } else {
        pv_stage1_scalar<<<B_ * T_, 64, 0, stream>>>(binsR, binsI, bandR, bandI,
                                                     c2pR, c2pI, out);
    }
    pv_iir<<<B_ * K_, 512, 0, stream>>>(out, tau);
}